// Round 9
// baseline (176.242 us; speedup 1.0000x reference)
//
#include <hip/hip_runtime.h>

typedef unsigned short u16;
typedef __bf16 bf16x8 __attribute__((ext_vector_type(8)));
typedef float f32x4 __attribute__((ext_vector_type(4)));
typedef unsigned short u16x8 __attribute__((ext_vector_type(8)));
typedef unsigned short u16x4 __attribute__((ext_vector_type(4)));

#define NB 8
#define NC 640
#define NN 4096
#define NL 77
#define NCD 768
#define NH 8
#define NDH 80

__device__ __forceinline__ u16 f2bf(float f) {
  unsigned u = __builtin_bit_cast(unsigned, f);
  u += 0x7fffu + ((u >> 16) & 1u);   // RNE
  return (u16)(u >> 16);
}

__device__ __forceinline__ f32x4 mfma16(bf16x8 a, bf16x8 b, f32x4 c) {
  return __builtin_amdgcn_mfma_f32_16x16x32_bf16(a, b, c, 0, 0, 0);
}

__device__ __forceinline__ void gload_lds16(const void* g, void* l) {
  __builtin_amdgcn_global_load_lds(
      (const __attribute__((address_space(1))) void*)g,
      (__attribute__((address_space(3))) void*)l, 16, 0, 0);
}

// ---------------- merged prep: [0,800) prep_w | [800,1760) kv (es-staged) | [1760,1888) sal
// prep_x is GONE: gemm_q reads hs directly (no xbf roundtrip).
__global__ __launch_bounds__(256) void k_prep(const float* __restrict__ ehs,
                                              const float* __restrict__ Wq,
                                              const float* __restrict__ Wk,
                                              const float* __restrict__ Wv,
                                              const float* __restrict__ Wo,
                                              u16* __restrict__ wqt,
                                              u16* __restrict__ wot,
                                              u16* __restrict__ kbf,
                                              u16* __restrict__ vtbf,
                                              float* __restrict__ sal) {
  __shared__ __align__(16) char smem[37888];
  const int bid = blockIdx.x;
  const int t = threadIdx.x;

  if (bid < 800) {
    // ---- prep_w: Wq,Wo (k,n) f32 -> (n,k) bf16; scale folded into Wq
    float(*tls)[33] = (float(*)[33])smem;
    const int which = bid / 400;
    const int rem = bid % 400;
    const float* in = which ? Wo : Wq;
    u16* outp = which ? wot : wqt;
    const float scale = which ? 1.0f : 0.11180339887498949f;  // 1/sqrt(80)
    const int n0 = (rem % 20) * 32, k0 = (rem / 20) * 32;
    const int r = t >> 3, c4 = (t & 7) * 4;
    float4 v = *(const float4*)(in + (size_t)(k0 + r) * NC + n0 + c4);
    tls[r][c4 + 0] = v.x; tls[r][c4 + 1] = v.y; tls[r][c4 + 2] = v.z; tls[r][c4 + 3] = v.w;
    __syncthreads();
    u16x4 o;
#pragma unroll
    for (int e = 0; e < 4; ++e) o[e] = f2bf(tls[c4 + e][r] * scale);
    *(u16x4*)(outp + (size_t)(n0 + r) * NC + k0 + c4) = o;
    return;
  }
  if (bid < 1760) {
    // ---- kv: K,V = ehs @ Wk/Wv (es-staged, R5-proven)
    // kbf (B,H,80l,80d) pad rows untouched (masked downstream);
    // vtbf (B,H,80d,96l) pad l-cols zeroed
    const int i = bid - 800;
    const int l = i % 96, cg = i / 96;
    if (l >= NL) {
      if (t < 64) {
        int c = cg * 64 + t;
        int h = c / NDH, d = c % NDH;
#pragma unroll
        for (int b = 0; b < NB; ++b)
          vtbf[(((size_t)(b * NH + h)) * NDH + d) * 96 + l] = 0;
      }
      return;
    }
    float(*es)[NCD] = (float(*)[NCD])smem;                       // 24 KB
    float(*comb)[64][17] = (float(*)[64][17])(smem + 24576);     // 13 KB
#pragma unroll
    for (int j = 0; j < 6; ++j) {
      int idx = (t + j * 256) * 4;
      int b = idx / NCD, k = idx % NCD;
      *(float4*)&es[b][k] = *(const float4*)(ehs + ((size_t)(b * NL + l)) * NCD + k);
    }
    __syncthreads();
    const int col = t & 63, kq = t >> 6;
    const int c = cg * 64 + col;
    float ak[NB], av[NB];
#pragma unroll
    for (int b = 0; b < NB; ++b) { ak[b] = 0.f; av[b] = 0.f; }
    const int kbeg = kq * 192, kend = kbeg + 192;
#pragma unroll 4
    for (int k = kbeg; k < kend; ++k) {
      float wk = Wk[(size_t)k * NC + c];
      float wv = Wv[(size_t)k * NC + c];
#pragma unroll
      for (int b = 0; b < NB; ++b) {
        ak[b] = fmaf(es[b][k], wk, ak[b]);
        av[b] = fmaf(es[b][k], wv, av[b]);
      }
    }
    if (kq) {
#pragma unroll
      for (int b = 0; b < NB; ++b) {
        comb[kq - 1][col][b] = ak[b];
        comb[kq - 1][col][8 + b] = av[b];
      }
    }
    __syncthreads();
    if (kq == 0) {
#pragma unroll
      for (int b = 0; b < NB; ++b) {
#pragma unroll
        for (int q = 0; q < 3; ++q) {
          ak[b] += comb[q][col][b];
          av[b] += comb[q][col][8 + b];
        }
      }
      const int h = c / NDH, d = c % NDH;
#pragma unroll
      for (int b = 0; b < NB; ++b) {
        kbf[(((size_t)(b * NH + h)) * 80 + l) * 80 + d] = f2bf(ak[b]);
        vtbf[(((size_t)(b * NH + h)) * NDH + d) * 96 + l] = f2bf(av[b]);
      }
    }
    return;
  }
  {
    // ---- saliency: softmax row-mean is exactly 1/L
    int i = (bid - 1760) * 256 + t;
    if (i < NB * NN) sal[i] = 1.0f / 77.0f;
  }
}

// ---------------- Gq: q = x @ Wq^T, x consumed DIRECTLY from hs (B,C,N) f32.
// 128x128 tile, 4 waves. A-operand: per-lane fragment gather from hs —
// lane(g,fr), fragment mt: 8 dword loads hs[b][k0+kk*32+g*8+j][n0+wm*64+mt*16+fr]
// (16 fr-lanes = 64B contiguous along n) + f2bf pack. No LDS for A, no transpose.
// B-operand: R5-proven gload_lds + T2 swizzle. Epilogue: operand-swapped MFMA,
// out bf16 (B,N,C). hs A-panel (327 KB) shared by 5 cb-blocks via XCD L2 (T1).
__global__ __launch_bounds__(256, 3) void k_gemm_q(const float* __restrict__ hs,
                                                   const u16* __restrict__ Bw,
                                                   u16* __restrict__ outb) {
  __shared__ __align__(16) u16 sB[128 * 64];
  const int bid = blockIdx.x;
  const int logical = (bid & 7) * 160 + (bid >> 3);  // T1 XCD swizzle (1280%8==0)
  const int cb = logical % 5, rb = logical / 5;
  const int r0 = rb * 128, c0 = cb * 128;
  const int t = threadIdx.x;
  const int w = t >> 6, lane = t & 63;
  const int wm = w >> 1, wn = w & 1;
  const int fr = lane & 15, g = lane >> 4;
  const int lr = lane >> 3, ls = lane & 7;
  const int sslot = ls ^ lr;  // T2 pre-swizzled k-slot for B
  const int b = r0 >> 12, n0 = r0 & 4095;  // 128 | 4096: tile never straddles b
  const int nbase = n0 + wm * 64 + fr;

  f32x4 acc[4][4];
  f32x4 z4 = {0.f, 0.f, 0.f, 0.f};
#pragma unroll
  for (int i = 0; i < 4; ++i)
#pragma unroll
    for (int j = 0; j < 4; ++j) acc[i][j] = z4;

  for (int ks = 0; ks < 10; ++ks) {
    const int k0 = ks * 64;
    // B staging (16 KB): 16 chunks of 8 rows
#pragma unroll
    for (int p = 0; p < 4; ++p) {
      int q = w * 4 + p;
      int row = q * 8 + lr;
      gload_lds16(Bw + (size_t)(c0 + row) * NC + k0 + sslot * 8, sB + q * 512);
    }
    // A fragments direct from hs + convert (issue all loads; compiler pipelines)
    bf16x8 af[4][2];
#pragma unroll
    for (int kk = 0; kk < 2; ++kk) {
      const float* hp = hs + (((size_t)(b * NC + k0 + kk * 32 + g * 8)) << 12) + nbase;
#pragma unroll
      for (int mt = 0; mt < 4; ++mt) {
        float tmp[8];
#pragma unroll
        for (int j = 0; j < 8; ++j) tmp[j] = hp[((size_t)j << 12) + mt * 16];
        u16x8 pk;
#pragma unroll
        for (int j = 0; j < 8; ++j) pk[j] = f2bf(tmp[j]);
        af[mt][kk] = __builtin_bit_cast(bf16x8, pk);
      }
    }
    asm volatile("s_waitcnt vmcnt(0)" ::: "memory");
    __syncthreads();
#pragma unroll
    for (int kk = 0; kk < 2; ++kk) {
      bf16x8 bfr[4];
#pragma unroll
      for (int nt = 0; nt < 4; ++nt) {
        int row = wn * 64 + nt * 16 + fr;
        bfr[nt] = *(const bf16x8*)((const char*)sB + row * 128 +
                                   ((kk * 64 + g * 16) ^ ((row & 7) << 4)));
      }
#pragma unroll
      for (int mt = 0; mt < 4; ++mt)
#pragma unroll
        for (int nt = 0; nt < 4; ++nt)
          acc[mt][nt] = mfma16(bfr[nt], af[mt][kk], acc[mt][nt]);  // D: row<->c, col<->n
    }
    __syncthreads();
  }
  // D[row=g*4+r <-> c][col=fr <-> n]; write (B,N,C), contiguous along c
#pragma unroll
  for (int mt = 0; mt < 4; ++mt) {
    int n = n0 + wm * 64 + mt * 16 + fr;
#pragma unroll
    for (int nt = 0; nt < 4; ++nt) {
      int cbs = c0 + wn * 64 + nt * 16 + g * 4;
      u16x4 o;
#pragma unroll
      for (int r2 = 0; r2 < 4; ++r2) o[r2] = f2bf(acc[mt][nt][r2]);
      *(u16x4*)(outb + ((size_t)(b * NN + n)) * NC + cbs) = o;
    }
  }
}

// ---------------- Go: out = attnO @ Wo^T + bo (R5-proven MODE-1, verbatim)
__global__ __launch_bounds__(256) void k_gemm_o(const u16* __restrict__ A,
                                                const u16* __restrict__ Bw,
                                                const float* __restrict__ bias,
                                                float* __restrict__ outf) {
  __shared__ __align__(16) u16 sA[128 * 64];
  __shared__ __align__(16) u16 sB[128 * 64];
  const int bid = blockIdx.x;
  const int logical = (bid & 7) * 160 + (bid >> 3);  // T1 XCD swizzle (1280%8==0)
  const int cb = logical % 5, rb = logical / 5;
  const int r0 = rb * 128, c0 = cb * 128;
  const int t = threadIdx.x;
  const int w = t >> 6, lane = t & 63;
  const int wm = w >> 1, wn = w & 1;
  const int fr = lane & 15, g = lane >> 4;
  const int lr = lane >> 3, ls = lane & 7;
  const int sslot = ls ^ lr;  // pre-swizzled k-slot (row&7 == lr)

  f32x4 acc[4][4];
  f32x4 z4 = {0.f, 0.f, 0.f, 0.f};
#pragma unroll
  for (int i = 0; i < 4; ++i)
#pragma unroll
    for (int j = 0; j < 4; ++j) acc[i][j] = z4;

  for (int ks = 0; ks < 10; ++ks) {
    const int k0 = ks * 64;
#pragma unroll
    for (int p = 0; p < 4; ++p) {
      int q = w * 4 + p;           // chunk: rows q*8 .. q*8+7
      int row = q * 8 + lr;
      gload_lds16(A + (size_t)(r0 + row) * NC + k0 + sslot * 8, sA + q * 512);
      gload_lds16(Bw + (size_t)(c0 + row) * NC + k0 + sslot * 8, sB + q * 512);
    }
    asm volatile("s_waitcnt vmcnt(0)" ::: "memory");
    __syncthreads();
#pragma unroll
    for (int kk = 0; kk < 2; ++kk) {
      bf16x8 af[4], bfr[4];
#pragma unroll
      for (int mt = 0; mt < 4; ++mt) {
        int row = wm * 64 + mt * 16 + fr;
        af[mt] = *(const bf16x8*)((const char*)sA + row * 128 +
                                  ((kk * 64 + g * 16) ^ ((row & 7) << 4)));
      }
#pragma unroll
      for (int nt = 0; nt < 4; ++nt) {
        int row = wn * 64 + nt * 16 + fr;
        bfr[nt] = *(const bf16x8*)((const char*)sB + row * 128 +
                                   ((kk * 64 + g * 16) ^ ((row & 7) << 4)));
      }
#pragma unroll
      for (int mt = 0; mt < 4; ++mt)
#pragma unroll
        for (int nt = 0; nt < 4; ++nt)
          acc[mt][nt] = mfma16(af[mt], bfr[nt], acc[mt][nt]);  // D: row<->n, col<->c
    }
    __syncthreads();
  }
  const int b = r0 >> 12, n0 = r0 & 4095;
  // D[row=g*4+r <-> n][col=fr <-> c]; write (B,C,N) f32 + bias
#pragma unroll
  for (int mt = 0; mt < 4; ++mt) {
    int n = n0 + wm * 64 + mt * 16 + g * 4;
#pragma unroll
    for (int nt = 0; nt < 4; ++nt) {
      int c = c0 + wn * 64 + nt * 16 + fr;
      float bv = bias[c];
      f32x4 o;
#pragma unroll
      for (int r2 = 0; r2 < 4; ++r2) o[r2] = acc[mt][nt][r2] + bv;
      *(f32x4*)(outf + (((size_t)(b * NC + c)) << 12) + n) = o;
    }
  }
}

// ---------------- A1: fused attention, one (b,h,64 q-rows) per block (unchanged)
__global__ __launch_bounds__(256) void k_attn(const u16* __restrict__ qbf,
                                              const u16* __restrict__ kbf,
                                              const u16* __restrict__ vtbf,
                                              u16* __restrict__ obf) {
  __shared__ __align__(16) u16 sP[4][16][104];
  const int bid = blockIdx.x;
  const int n0 = (bid & 63) * 64, h = (bid >> 6) & 7, b = bid >> 9;
  const int t = threadIdx.x, w = t >> 6, lane = t & 63;
  const int fr = lane & 15, g = lane >> 4;

  const size_t qrow = ((size_t)(b * NN + n0 + w * 16 + fr)) * NC + h * NDH;
  bf16x8 qf[3];
#pragma unroll
  for (int kk = 0; kk < 3; ++kk) {
    int d0 = kk * 32 + g * 8;
    bf16x8 v = {};
    if (d0 < NDH) v = *(const bf16x8*)(qbf + qrow + d0);
    qf[kk] = v;
  }
  const size_t kbase = ((size_t)(b * NH + h)) * (80 * 80);
  f32x4 s[5];
  f32x4 z4 = {0.f, 0.f, 0.f, 0.f};
#pragma unroll
  for (int nt = 0; nt < 5; ++nt) s[nt] = z4;
#pragma unroll
  for (int nt = 0; nt < 5; ++nt) {
    const u16* krow = kbf + kbase + (size_t)(nt * 16 + fr) * 80;
#pragma unroll
    for (int kk = 0; kk < 3; ++kk) {
      int d0 = kk * 32 + g * 8;
      bf16x8 kv = {};
      if (d0 < NDH) kv = *(const bf16x8*)(krow + d0);
      s[nt] = mfma16(kv, qf[kk], s[nt]);
    }
  }
  const size_t vbase = ((size_t)(b * NH + h)) * (80 * 96);
  bf16x8 vf[5][3];
#pragma unroll
  for (int nt = 0; nt < 5; ++nt)
#pragma unroll
    for (int kk = 0; kk < 3; ++kk)
      vf[nt][kk] = *(const bf16x8*)(vtbf + vbase + (size_t)(nt * 16 + fr) * 96 +
                                    kk * 32 + g * 8);
  float sum = 0.f;
#pragma unroll
  for (int nt = 0; nt < 5; ++nt)
#pragma unroll
    for (int r = 0; r < 4; ++r) {
      int l = nt * 16 + g * 4 + r;
      float ev = (l < NL) ? __expf(s[nt][r]) : 0.f;
      s[nt][r] = ev;
      sum += ev;
    }
  sum += __shfl_xor(sum, 16);
  sum += __shfl_xor(sum, 32);
  float inv = 1.0f / sum;
#pragma unroll
  for (int nt = 0; nt < 5; ++nt) {
    u16x4 o;
#pragma unroll
    for (int r = 0; r < 4; ++r) o[r] = f2bf(s[nt][r] * inv);
    *(u16x4*)&sP[w][fr][nt * 16 + g * 4] = o;
  }
  __syncthreads();
  bf16x8 ap[3];
#pragma unroll
  for (int kk = 0; kk < 3; ++kk) {
    int l0 = kk * 32 + g * 8;
    bf16x8 v = {};
    if (l0 < 80) v = *(const bf16x8*)&sP[w][fr][l0];
    ap[kk] = v;
  }
  f32x4 o[5];
#pragma unroll
  for (int nt = 0; nt < 5; ++nt) o[nt] = z4;
#pragma unroll
  for (int nt = 0; nt < 5; ++nt)
#pragma unroll
    for (int kk = 0; kk < 3; ++kk)
      o[nt] = mfma16(ap[kk], vf[nt][kk], o[nt]);
#pragma unroll
  for (int nt = 0; nt < 5; ++nt)
#pragma unroll
    for (int r = 0; r < 4; ++r)
      obf[((size_t)(b * NN + n0 + w * 16 + g * 4 + r)) * NC + h * NDH + nt * 16 + fr] =
          f2bf(o[nt][r]);
}

extern "C" void kernel_launch(void* const* d_in, const int* in_sizes, int n_in,
                              void* d_out, int out_size, void* d_ws, size_t ws_size,
                              hipStream_t stream) {
  const float* hs  = (const float*)d_in[0];
  const float* ehs = (const float*)d_in[1];
  const float* Wq  = (const float*)d_in[2];
  const float* Wk  = (const float*)d_in[3];
  const float* Wv  = (const float*)d_in[4];
  const float* Wo  = (const float*)d_in[5];
  const float* bo  = (const float*)d_in[6];
  float* out = (float*)d_out;
  float* sal = out + (size_t)NB * NC * NN;

  u16* ws16 = (u16*)d_ws;
  const size_t xn = (size_t)NB * NN * NC;  // 20,971,520
  u16* obf = ws16;
  u16* qbf = ws16 + xn;
  u16* wqt = qbf + xn;
  u16* wot = wqt + (size_t)NC * NC;
  u16* kbf = wot + (size_t)NC * NC;                 // B*H*80*80
  u16* vtbf = kbf + (size_t)NB * NH * 80 * 80;      // B*H*80*96

  k_prep<<<1888, 256, 0, stream>>>(ehs, Wq, Wk, Wv, Wo,
                                   wqt, wot, kbf, vtbf, sal);
  k_gemm_q<<<1280, 256, 0, stream>>>(hs, wqt, qbf);
  k_attn<<<NB * NH * 64, 256, 0, stream>>>(qbf, kbf, vtbf, obf);
  k_gemm_o<<<1280, 256, 0, stream>>>(obf, wot, bo, out);
}

// Round 10
// 168.908 us; speedup vs baseline: 1.0434x; 1.0434x over previous
//
#include <hip/hip_runtime.h>

typedef unsigned short u16;
typedef __bf16 bf16x8 __attribute__((ext_vector_type(8)));
typedef float f32x4 __attribute__((ext_vector_type(4)));
typedef unsigned short u16x8 __attribute__((ext_vector_type(8)));
typedef unsigned short u16x4 __attribute__((ext_vector_type(4)));

#define NB 8
#define NC 640
#define NN 4096
#define NL 77
#define NCD 768
#define NH 8
#define NDH 80

__device__ __forceinline__ u16 f2bf(float f) {
  unsigned u = __builtin_bit_cast(unsigned, f);
  u += 0x7fffu + ((u >> 16) & 1u);   // RNE
  return (u16)(u >> 16);
}

__device__ __forceinline__ f32x4 mfma16(bf16x8 a, bf16x8 b, f32x4 c) {
  return __builtin_amdgcn_mfma_f32_16x16x32_bf16(a, b, c, 0, 0, 0);
}

__device__ __forceinline__ void gload_lds16(const void* g, void* l) {
  __builtin_amdgcn_global_load_lds(
      (const __attribute__((address_space(1))) void*)g,
      (__attribute__((address_space(3))) void*)l, 16, 0, 0);
}

// ---------------- merged prep (R5 structure; ONLY prep_x tile fattened 64n->128n):
// [0,800) prep_w | [800,1760) kv (es-staged) | [1760,4320) fat prep_x | [4320,4448) sal
__global__ __launch_bounds__(256) void k_prep(const float* __restrict__ hs,
                                              const float* __restrict__ ehs,
                                              const float* __restrict__ Wq,
                                              const float* __restrict__ Wk,
                                              const float* __restrict__ Wv,
                                              const float* __restrict__ Wo,
                                              u16* __restrict__ xbf,
                                              u16* __restrict__ wqt,
                                              u16* __restrict__ wot,
                                              u16* __restrict__ kbf,
                                              u16* __restrict__ vtbf,
                                              float* __restrict__ sal) {
  __shared__ __align__(16) char smem[37888];
  const int bid = blockIdx.x;
  const int t = threadIdx.x;

  if (bid < 800) {
    // ---- prep_w: Wq,Wo (k,n) f32 -> (n,k) bf16; scale folded into Wq
    float(*tls)[33] = (float(*)[33])smem;
    const int which = bid / 400;
    const int rem = bid % 400;
    const float* in = which ? Wo : Wq;
    u16* outp = which ? wot : wqt;
    const float scale = which ? 1.0f : 0.11180339887498949f;  // 1/sqrt(80)
    const int n0 = (rem % 20) * 32, k0 = (rem / 20) * 32;
    const int r = t >> 3, c4 = (t & 7) * 4;
    float4 v = *(const float4*)(in + (size_t)(k0 + r) * NC + n0 + c4);
    tls[r][c4 + 0] = v.x; tls[r][c4 + 1] = v.y; tls[r][c4 + 2] = v.z; tls[r][c4 + 3] = v.w;
    __syncthreads();
    u16x4 o;
#pragma unroll
    for (int e = 0; e < 4; ++e) o[e] = f2bf(tls[c4 + e][r] * scale);
    *(u16x4*)(outp + (size_t)(n0 + r) * NC + k0 + c4) = o;
    return;
  }
  if (bid < 1760) {
    // ---- kv: K,V = ehs @ Wk/Wv (es-staged, R5-proven verbatim)
    // kbf (B,H,80l,80d) pad rows untouched (masked downstream);
    // vtbf (B,H,80d,96l) pad l-cols zeroed
    const int i = bid - 800;
    const int l = i % 96, cg = i / 96;
    if (l >= NL) {
      if (t < 64) {
        int c = cg * 64 + t;
        int h = c / NDH, d = c % NDH;
#pragma unroll
        for (int b = 0; b < NB; ++b)
          vtbf[(((size_t)(b * NH + h)) * NDH + d) * 96 + l] = 0;
      }
      return;
    }
    float(*es)[NCD] = (float(*)[NCD])smem;                       // 24 KB
    float(*comb)[64][17] = (float(*)[64][17])(smem + 24576);     // 13 KB
#pragma unroll
    for (int j = 0; j < 6; ++j) {
      int idx = (t + j * 256) * 4;
      int b = idx / NCD, k = idx % NCD;
      *(float4*)&es[b][k] = *(const float4*)(ehs + ((size_t)(b * NL + l)) * NCD + k);
    }
    __syncthreads();
    const int col = t & 63, kq = t >> 6;
    const int c = cg * 64 + col;
    float ak[NB], av[NB];
#pragma unroll
    for (int b = 0; b < NB; ++b) { ak[b] = 0.f; av[b] = 0.f; }
    const int kbeg = kq * 192, kend = kbeg + 192;
#pragma unroll 4
    for (int k = kbeg; k < kend; ++k) {
      float wk = Wk[(size_t)k * NC + c];
      float wv = Wv[(size_t)k * NC + c];
#pragma unroll
      for (int b = 0; b < NB; ++b) {
        ak[b] = fmaf(es[b][k], wk, ak[b]);
        av[b] = fmaf(es[b][k], wv, av[b]);
      }
    }
    if (kq) {
#pragma unroll
      for (int b = 0; b < NB; ++b) {
        comb[kq - 1][col][b] = ak[b];
        comb[kq - 1][col][8 + b] = av[b];
      }
    }
    __syncthreads();
    if (kq == 0) {
#pragma unroll
      for (int b = 0; b < NB; ++b) {
#pragma unroll
        for (int q = 0; q < 3; ++q) {
          ak[b] += comb[q][col][b];
          av[b] += comb[q][col][8 + b];
        }
      }
      const int h = c / NDH, d = c % NDH;
#pragma unroll
      for (int b = 0; b < NB; ++b) {
        kbf[(((size_t)(b * NH + h)) * 80 + l) * 80 + d] = f2bf(ak[b]);
        vtbf[(((size_t)(b * NH + h)) * NDH + d) * 96 + l] = f2bf(av[b]);
      }
    }
    return;
  }
  if (bid < 4320) {
    // ---- fat prep_x: hs (B,C,N) f32 -> xbf (B,N,C) bf16; 64c x 128n per block.
    // 8 float4 in flight per thread (2x R5's MLP), half the barriers per byte.
    // [64][133]: read stride 532B == 20 mod 32 banks -> 8 banks/16 lanes, 2-way (free)
    float(*tls)[133] = (float(*)[133])smem;  // 34 KB
    const int i = bid - 1760;
    const int n0 = (i % 32) * 128;
    const int c0 = ((i / 32) % 10) * 64;
    const int b = i / 320;
    const int rr = t >> 4;            // 0..15
    const int cl = t & 15;
#pragma unroll
    for (int p = 0; p < 4; ++p) {
      int c = p * 16 + rr;
      const float* hp = hs + ((size_t)(b * NC + c0 + c) << 12) + n0 + cl * 8;
      float4 v0 = *(const float4*)hp;
      float4 v1 = *(const float4*)(hp + 4);
      *(float4*)&tls[c][cl * 8] = v0;
      *(float4*)&tls[c][cl * 8 + 4] = v1;
    }
    __syncthreads();
    const int cc2 = cl * 4;
#pragma unroll
    for (int p2 = 0; p2 < 8; ++p2) {
      int n = p2 * 16 + rr;
      u16x4 o;
#pragma unroll
      for (int e = 0; e < 4; ++e) o[e] = f2bf(tls[cc2 + e][n]);
      *(u16x4*)(xbf + ((size_t)(b * NN + n0 + n)) * NC + c0 + cc2) = o;
    }
    return;
  }
  {
    // ---- saliency: softmax row-mean is exactly 1/L
    int i = (bid - 4320) * 256 + t;
    if (i < NB * NN) sal[i] = 1.0f / 77.0f;
  }
}

// ---------------- G: C(32768x640) = A(32768x640,bf16) @ Bw^T(640x640 [n][k],bf16)
// R5-proven single-buffer structure: 128x128, 4 waves, gload_lds + vmcnt(0) +
// __syncthreads per K-tile; T1 XCD swizzle; T2 pre-swizzled source + swizzled read.
// MODE 0: out bf16 (B,N,C)  (operand-swapped MFMA)
// MODE 1: out f32  (B,C,N) + bias
template <int MODE>
__global__ __launch_bounds__(256) void k_gemm(const u16* __restrict__ A,
                                              const u16* __restrict__ Bw,
                                              const float* __restrict__ bias,
                                              u16* __restrict__ outb,
                                              float* __restrict__ outf) {
  __shared__ __align__(16) u16 sA[128 * 64];
  __shared__ __align__(16) u16 sB[128 * 64];
  const int bid = blockIdx.x;
  const int logical = (bid & 7) * 160 + (bid >> 3);  // T1 XCD swizzle (1280%8==0)
  const int cb = logical % 5, rb = logical / 5;
  const int r0 = rb * 128, c0 = cb * 128;
  const int t = threadIdx.x;
  const int w = t >> 6, lane = t & 63;
  const int wm = w >> 1, wn = w & 1;
  const int fr = lane & 15, g = lane >> 4;
  const int lr = lane >> 3, ls = lane & 7;
  const int sslot = ls ^ lr;  // pre-swizzled k-slot (row&7 == lr)

  f32x4 acc[4][4];
  f32x4 z4 = {0.f, 0.f, 0.f, 0.f};
#pragma unroll
  for (int i = 0; i < 4; ++i)
#pragma unroll
    for (int j = 0; j < 4; ++j) acc[i][j] = z4;

  for (int ks = 0; ks < 10; ++ks) {
    const int k0 = ks * 64;
#pragma unroll
    for (int p = 0; p < 4; ++p) {
      int q = w * 4 + p;           // chunk: rows q*8 .. q*8+7
      int row = q * 8 + lr;
      gload_lds16(A + (size_t)(r0 + row) * NC + k0 + sslot * 8, sA + q * 512);
      gload_lds16(Bw + (size_t)(c0 + row) * NC + k0 + sslot * 8, sB + q * 512);
    }
    asm volatile("s_waitcnt vmcnt(0)" ::: "memory");
    __syncthreads();
#pragma unroll
    for (int kk = 0; kk < 2; ++kk) {
      bf16x8 af[4], bfr[4];
#pragma unroll
      for (int mt = 0; mt < 4; ++mt) {
        int row = wm * 64 + mt * 16 + fr;
        af[mt] = *(const bf16x8*)((const char*)sA + row * 128 +
                                  ((kk * 64 + g * 16) ^ ((row & 7) << 4)));
      }
#pragma unroll
      for (int nt = 0; nt < 4; ++nt) {
        int row = wn * 64 + nt * 16 + fr;
        bfr[nt] = *(const bf16x8*)((const char*)sB + row * 128 +
                                   ((kk * 64 + g * 16) ^ ((row & 7) << 4)));
      }
#pragma unroll
      for (int mt = 0; mt < 4; ++mt)
#pragma unroll
        for (int nt = 0; nt < 4; ++nt) {
          if (MODE == 0)
            acc[mt][nt] = mfma16(bfr[nt], af[mt], acc[mt][nt]);  // D: row<->c, col<->n
          else
            acc[mt][nt] = mfma16(af[mt], bfr[nt], acc[mt][nt]);  // D: row<->n, col<->c
        }
    }
    __syncthreads();
  }
  const int b = r0 >> 12, n0 = r0 & 4095;
  if (MODE == 0) {
    // D[row=g*4+r <-> c][col=fr <-> n]; write (B,N,C), contiguous along c
#pragma unroll
    for (int mt = 0; mt < 4; ++mt) {
      int n = n0 + wm * 64 + mt * 16 + fr;
#pragma unroll
      for (int nt = 0; nt < 4; ++nt) {
        int cbs = c0 + wn * 64 + nt * 16 + g * 4;
        u16x4 o;
#pragma unroll
        for (int r2 = 0; r2 < 4; ++r2) o[r2] = f2bf(acc[mt][nt][r2]);
        *(u16x4*)(outb + ((size_t)(b * NN + n)) * NC + cbs) = o;
      }
    }
  } else {
    // D[row=g*4+r <-> n][col=fr <-> c]; write (B,C,N) f32 + bias
#pragma unroll
    for (int mt = 0; mt < 4; ++mt) {
      int n = n0 + wm * 64 + mt * 16 + g * 4;
#pragma unroll
      for (int nt = 0; nt < 4; ++nt) {
        int c = c0 + wn * 64 + nt * 16 + fr;
        float bv = bias[c];
        f32x4 o;
#pragma unroll
        for (int r2 = 0; r2 < 4; ++r2) o[r2] = acc[mt][nt][r2] + bv;
        *(f32x4*)(outf + (((size_t)(b * NC + c)) << 12) + n) = o;
      }
    }
  }
}

// ---------------- A1: fused attention, one (b,h,64 q-rows) per block (R5 verbatim)
__global__ __launch_bounds__(256) void k_attn(const u16* __restrict__ qbf,
                                              const u16* __restrict__ kbf,
                                              const u16* __restrict__ vtbf,
                                              u16* __restrict__ obf) {
  __shared__ __align__(16) u16 sP[4][16][104];
  const int bid = blockIdx.x;
  const int n0 = (bid & 63) * 64, h = (bid >> 6) & 7, b = bid >> 9;
  const int t = threadIdx.x, w = t >> 6, lane = t & 63;
  const int fr = lane & 15, g = lane >> 4;

  const size_t qrow = ((size_t)(b * NN + n0 + w * 16 + fr)) * NC + h * NDH;
  bf16x8 qf[3];
#pragma unroll
  for (int kk = 0; kk < 3; ++kk) {
    int d0 = kk * 32 + g * 8;
    bf16x8 v = {};
    if (d0 < NDH) v = *(const bf16x8*)(qbf + qrow + d0);
    qf[kk] = v;
  }
  const size_t kbase = ((size_t)(b * NH + h)) * (80 * 80);
  f32x4 s[5];
  f32x4 z4 = {0.f, 0.f, 0.f, 0.f};
#pragma unroll
  for (int nt = 0; nt < 5; ++nt) s[nt] = z4;
#pragma unroll
  for (int nt = 0; nt < 5; ++nt) {
    const u16* krow = kbf + kbase + (size_t)(nt * 16 + fr) * 80;
#pragma unroll
    for (int kk = 0; kk < 3; ++kk) {
      int d0 = kk * 32 + g * 8;
      bf16x8 kv = {};
      if (d0 < NDH) kv = *(const bf16x8*)(krow + d0);
      s[nt] = mfma16(kv, qf[kk], s[nt]);
    }
  }
  const size_t vbase = ((size_t)(b * NH + h)) * (80 * 96);
  bf16x8 vf[5][3];
#pragma unroll
  for (int nt = 0; nt < 5; ++nt)
#pragma unroll
    for (int kk = 0; kk < 3; ++kk)
      vf[nt][kk] = *(const bf16x8*)(vtbf + vbase + (size_t)(nt * 16 + fr) * 96 +
                                    kk * 32 + g * 8);
  float sum = 0.f;
#pragma unroll
  for (int nt = 0; nt < 5; ++nt)
#pragma unroll
    for (int r = 0; r < 4; ++r) {
      int l = nt * 16 + g * 4 + r;
      float ev = (l < NL) ? __expf(s[nt][r]) : 0.f;
      s[nt][r] = ev;
      sum += ev;
    }
  sum += __shfl_xor(sum, 16);
  sum += __shfl_xor(sum, 32);
  float inv = 1.0f / sum;
#pragma unroll
  for (int nt = 0; nt < 5; ++nt) {
    u16x4 o;
#pragma unroll
    for (int r = 0; r < 4; ++r) o[r] = f2bf(s[nt][r] * inv);
    *(u16x4*)&sP[w][fr][nt * 16 + g * 4] = o;
  }
  __syncthreads();
  bf16x8 ap[3];
#pragma unroll
  for (int kk = 0; kk < 3; ++kk) {
    int l0 = kk * 32 + g * 8;
    bf16x8 v = {};
    if (l0 < 80) v = *(const bf16x8*)&sP[w][fr][l0];
    ap[kk] = v;
  }
  f32x4 o[5];
#pragma unroll
  for (int nt = 0; nt < 5; ++nt) o[nt] = z4;
#pragma unroll
  for (int nt = 0; nt < 5; ++nt)
#pragma unroll
    for (int kk = 0; kk < 3; ++kk)
      o[nt] = mfma16(ap[kk], vf[nt][kk], o[nt]);
#pragma unroll
  for (int nt = 0; nt < 5; ++nt)
#pragma unroll
    for (int r = 0; r < 4; ++r)
      obf[((size_t)(b * NN + n0 + w * 16 + g * 4 + r)) * NC + h * NDH + nt * 16 + fr] =
          f2bf(o[nt][r]);
}

extern "C" void kernel_launch(void* const* d_in, const int* in_sizes, int n_in,
                              void* d_out, int out_size, void* d_ws, size_t ws_size,
                              hipStream_t stream) {
  const float* hs  = (const float*)d_in[0];
  const float* ehs = (const float*)d_in[1];
  const float* Wq  = (const float*)d_in[2];
  const float* Wk  = (const float*)d_in[3];
  const float* Wv  = (const float*)d_in[4];
  const float* Wo  = (const float*)d_in[5];
  const float* bo  = (const float*)d_in[6];
  float* out = (float*)d_out;
  float* sal = out + (size_t)NB * NC * NN;

  u16* ws16 = (u16*)d_ws;
  const size_t xn = (size_t)NB * NN * NC;  // 20,971,520
  u16* xbf = ws16;            // also obf (xbf dead after gemm<0>)
  u16* qbf = ws16 + xn;
  u16* wqt = qbf + xn;
  u16* wot = wqt + (size_t)NC * NC;
  u16* kbf = wot + (size_t)NC * NC;                 // B*H*80*80
  u16* vtbf = kbf + (size_t)NB * NH * 80 * 80;      // B*H*80*96
  u16* obf = xbf;

  k_prep<<<4448, 256, 0, stream>>>(hs, ehs, Wq, Wk, Wv, Wo,
                                   xbf, wqt, wot, kbf, vtbf, sal);
  k_gemm<0><<<1280, 256, 0, stream>>>(xbf, wqt, nullptr, qbf, nullptr);
  k_attn<<<NB * NH * 64, 256, 0, stream>>>(qbf, kbf, vtbf, obf);
  k_gemm<1><<<1280, 256, 0, stream>>>(obf, wot, bo, nullptr, out);
}

// Round 11
// 164.883 us; speedup vs baseline: 1.0689x; 1.0244x over previous
//
#include <hip/hip_runtime.h>

typedef unsigned short u16;
typedef __bf16 bf16x8 __attribute__((ext_vector_type(8)));
typedef float f32x4 __attribute__((ext_vector_type(4)));
typedef unsigned short u16x8 __attribute__((ext_vector_type(8)));
typedef unsigned short u16x4 __attribute__((ext_vector_type(4)));

#define NB 8
#define NC 640
#define NN 4096
#define NL 77
#define NCD 768
#define NH 8
#define NDH 80

__device__ __forceinline__ u16 f2bf(float f) {
  unsigned u = __builtin_bit_cast(unsigned, f);
  u += 0x7fffu + ((u >> 16) & 1u);   // RNE
  return (u16)(u >> 16);
}

__device__ __forceinline__ f32x4 mfma16(bf16x8 a, bf16x8 b, f32x4 c) {
  return __builtin_amdgcn_mfma_f32_16x16x32_bf16(a, b, c, 0, 0, 0);
}

__device__ __forceinline__ void gload_lds16(const void* g, void* l) {
  __builtin_amdgcn_global_load_lds(
      (const __attribute__((address_space(1))) void*)g,
      (__attribute__((address_space(3))) void*)l, 16, 0, 0);
}

// ---------------- k_prep: [0,800) prep_w | [800,5920) thin prep_x | [5920,6048) sal
// kv moved out -> smem union = 17.7 KB -> 8 blocks/CU capacity for the
// latency-bound prep_x phase (vs 4 at R5's 37.9 KB).
__global__ __launch_bounds__(256) void k_prep(const float* __restrict__ hs,
                                              const float* __restrict__ Wq,
                                              const float* __restrict__ Wo,
                                              u16* __restrict__ xbf,
                                              u16* __restrict__ wqt,
                                              u16* __restrict__ wot,
                                              float* __restrict__ sal) {
  __shared__ __align__(16) char smem[17664];
  const int bid = blockIdx.x;
  const int t = threadIdx.x;

  if (bid < 800) {
    // ---- prep_w: Wq,Wo (k,n) f32 -> (n,k) bf16; scale folded into Wq
    float(*tls)[33] = (float(*)[33])smem;
    const int which = bid / 400;
    const int rem = bid % 400;
    const float* in = which ? Wo : Wq;
    u16* outp = which ? wot : wqt;
    const float scale = which ? 1.0f : 0.11180339887498949f;  // 1/sqrt(80)
    const int n0 = (rem % 20) * 32, k0 = (rem / 20) * 32;
    const int r = t >> 3, c4 = (t & 7) * 4;
    float4 v = *(const float4*)(in + (size_t)(k0 + r) * NC + n0 + c4);
    tls[r][c4 + 0] = v.x; tls[r][c4 + 1] = v.y; tls[r][c4 + 2] = v.z; tls[r][c4 + 3] = v.w;
    __syncthreads();
    u16x4 o;
#pragma unroll
    for (int e = 0; e < 4; ++e) o[e] = f2bf(tls[c4 + e][r] * scale);
    *(u16x4*)(outp + (size_t)(n0 + r) * NC + k0 + c4) = o;
    return;
  }
  if (bid < 5920) {
    // ---- thin prep_x (R5-proven): hs (B,C,N) f32 -> xbf (B,N,C) bf16
    float(*tls)[69] = (float(*)[69])smem;  // stride 69: 2-way bank alias (free)
    const int i = bid - 800;
    const int n0 = (i % 64) * 64;
    const int c0 = ((i / 64) % 10) * 64;
    const int b = i / 640;
    const int rr = t >> 4;
    const int cc = (t & 15) * 4;
#pragma unroll
    for (int p = 0; p < 4; ++p) {
      int c = p * 16 + rr;
      float4 v = *(const float4*)(hs + ((size_t)(b * NC + c0 + c) << 12) + n0 + cc);
      *(float4*)&tls[c][cc] = v;
    }
    __syncthreads();
#pragma unroll
    for (int p = 0; p < 4; ++p) {
      int n = p * 16 + rr;
      u16x4 o;
#pragma unroll
      for (int e = 0; e < 4; ++e) o[e] = f2bf(tls[cc + e][n]);
      *(u16x4*)(xbf + ((size_t)(b * NN + n0 + n)) * NC + c0 + cc) = o;
    }
    return;
  }
  {
    // ---- saliency: softmax row-mean is exactly 1/L
    int i = (bid - 5920) * 256 + t;
    if (i < NB * NN) sal[i] = 1.0f / 77.0f;
  }
}

// ---------------- k_kvg0: [0,960) kv | [960,2240) gemm<0>
// kv (VALU-bound) co-runs with gemm<0> (MFMA/mem-bound) on the same CUs —
// m114 co-issue removes kv's ~12 us serial residence. Data-independent:
// kv: ehs->kbf/vtbf; gemm: xbf,wqt->qbf. Static smem 32 KB (gemm) >= kv's
// 24 KB (comb aliases es after a barrier) -> gemm keeps 5 blocks/CU.
__global__ __launch_bounds__(256) void k_kvg0(const float* __restrict__ ehs,
                                              const float* __restrict__ Wk,
                                              const float* __restrict__ Wv,
                                              u16* __restrict__ kbf,
                                              u16* __restrict__ vtbf,
                                              const u16* __restrict__ A,
                                              const u16* __restrict__ Bw,
                                              u16* __restrict__ outb) {
  __shared__ __align__(16) char smem[32768];
  const int bid = blockIdx.x;
  const int t = threadIdx.x;

  if (bid < 960) {
    // ---- kv: K,V = ehs @ Wk/Wv (es-staged; comb ALIASES es, extra barrier)
    // kbf (B,H,80l,80d) pad rows untouched (masked downstream);
    // vtbf (B,H,80d,96l) pad l-cols zeroed
    const int l = bid % 96, cg = bid / 96;
    if (l >= NL) {
      if (t < 64) {
        int c = cg * 64 + t;
        int h = c / NDH, d = c % NDH;
#pragma unroll
        for (int b = 0; b < NB; ++b)
          vtbf[(((size_t)(b * NH + h)) * NDH + d) * 96 + l] = 0;
      }
      return;
    }
    float(*es)[NCD] = (float(*)[NCD])smem;            // 24 KB
    float(*comb)[64][17] = (float(*)[64][17])smem;    // 13 KB, aliases es (dead)
#pragma unroll
    for (int j = 0; j < 6; ++j) {
      int idx = (t + j * 256) * 4;
      int b = idx / NCD, k = idx % NCD;
      *(float4*)&es[b][k] = *(const float4*)(ehs + ((size_t)(b * NL + l)) * NCD + k);
    }
    __syncthreads();
    const int col = t & 63, kq = t >> 6;
    const int c = cg * 64 + col;
    float ak[NB], av[NB];
#pragma unroll
    for (int b = 0; b < NB; ++b) { ak[b] = 0.f; av[b] = 0.f; }
    const int kbeg = kq * 192, kend = kbeg + 192;
#pragma unroll 4
    for (int k = kbeg; k < kend; ++k) {
      float wk = Wk[(size_t)k * NC + c];
      float wv = Wv[(size_t)k * NC + c];
#pragma unroll
      for (int b = 0; b < NB; ++b) {
        ak[b] = fmaf(es[b][k], wk, ak[b]);
        av[b] = fmaf(es[b][k], wv, av[b]);
      }
    }
    __syncthreads();  // all waves done READING es before comb overwrites it
    if (kq) {
#pragma unroll
      for (int b = 0; b < NB; ++b) {
        comb[kq - 1][col][b] = ak[b];
        comb[kq - 1][col][8 + b] = av[b];
      }
    }
    __syncthreads();
    if (kq == 0) {
#pragma unroll
      for (int b = 0; b < NB; ++b) {
#pragma unroll
        for (int q = 0; q < 3; ++q) {
          ak[b] += comb[q][col][b];
          av[b] += comb[q][col][8 + b];
        }
      }
      const int h = c / NDH, d = c % NDH;
#pragma unroll
      for (int b = 0; b < NB; ++b) {
        kbf[(((size_t)(b * NH + h)) * 80 + l) * 80 + d] = f2bf(ak[b]);
        vtbf[(((size_t)(b * NH + h)) * NDH + d) * 96 + l] = f2bf(av[b]);
      }
    }
    return;
  }

  // ---- gemm<0>: q = x @ Wq^T (R5-proven 128x128 single-buffer structure)
  u16* sA = (u16*)smem;            // 16 KB
  u16* sB = (u16*)(smem + 16384);  // 16 KB
  const int bid2 = bid - 960;
  const int logical = (bid2 & 7) * 160 + (bid2 >> 3);  // T1 XCD swizzle (1280%8==0)
  const int cb = logical % 5, rb = logical / 5;
  const int r0 = rb * 128, c0 = cb * 128;
  const int w = t >> 6, lane = t & 63;
  const int wm = w >> 1, wn = w & 1;
  const int fr = lane & 15, g = lane >> 4;
  const int lr = lane >> 3, ls = lane & 7;
  const int sslot = ls ^ lr;  // T2 pre-swizzled k-slot (row&7 == lr)

  f32x4 acc[4][4];
  f32x4 z4 = {0.f, 0.f, 0.f, 0.f};
#pragma unroll
  for (int i = 0; i < 4; ++i)
#pragma unroll
    for (int j = 0; j < 4; ++j) acc[i][j] = z4;

  for (int ks = 0; ks < 10; ++ks) {
    const int k0 = ks * 64;
#pragma unroll
    for (int p = 0; p < 4; ++p) {
      int q = w * 4 + p;           // chunk: rows q*8 .. q*8+7
      int row = q * 8 + lr;
      gload_lds16(A + (size_t)(r0 + row) * NC + k0 + sslot * 8, sA + q * 512);
      gload_lds16(Bw + (size_t)(c0 + row) * NC + k0 + sslot * 8, sB + q * 512);
    }
    asm volatile("s_waitcnt vmcnt(0)" ::: "memory");
    __syncthreads();
#pragma unroll
    for (int kk = 0; kk < 2; ++kk) {
      bf16x8 af[4], bfr[4];
#pragma unroll
      for (int mt = 0; mt < 4; ++mt) {
        int row = wm * 64 + mt * 16 + fr;
        af[mt] = *(const bf16x8*)((const char*)sA + row * 128 +
                                  ((kk * 64 + g * 16) ^ ((row & 7) << 4)));
      }
#pragma unroll
      for (int nt = 0; nt < 4; ++nt) {
        int row = wn * 64 + nt * 16 + fr;
        bfr[nt] = *(const bf16x8*)((const char*)sB + row * 128 +
                                   ((kk * 64 + g * 16) ^ ((row & 7) << 4)));
      }
#pragma unroll
      for (int mt = 0; mt < 4; ++mt)
#pragma unroll
        for (int nt = 0; nt < 4; ++nt)
          acc[mt][nt] = mfma16(bfr[nt], af[mt], acc[mt][nt]);  // D: row<->c, col<->n
    }
    __syncthreads();
  }
  const int b = r0 >> 12, n0 = r0 & 4095;
  // D[row=g*4+r <-> c][col=fr <-> n]; write (B,N,C), contiguous along c
#pragma unroll
  for (int mt = 0; mt < 4; ++mt) {
    int n = n0 + wm * 64 + mt * 16 + fr;
#pragma unroll
    for (int nt = 0; nt < 4; ++nt) {
      int cbs = c0 + wn * 64 + nt * 16 + g * 4;
      u16x4 o;
#pragma unroll
      for (int r2 = 0; r2 < 4; ++r2) o[r2] = f2bf(acc[mt][nt][r2]);
      *(u16x4*)(outb + ((size_t)(b * NN + n)) * NC + cbs) = o;
    }
  }
}

// ---------------- Go: out = attnO @ Wo^T + bo (R5-proven MODE-1)
__global__ __launch_bounds__(256) void k_gemm_o(const u16* __restrict__ A,
                                                const u16* __restrict__ Bw,
                                                const float* __restrict__ bias,
                                                float* __restrict__ outf) {
  __shared__ __align__(16) u16 sA[128 * 64];
  __shared__ __align__(16) u16 sB[128 * 64];
  const int bid = blockIdx.x;
  const int logical = (bid & 7) * 160 + (bid >> 3);  // T1 XCD swizzle (1280%8==0)
  const int cb = logical % 5, rb = logical / 5;
  const int r0 = rb * 128, c0 = cb * 128;
  const int t = threadIdx.x;
  const int w = t >> 6, lane = t & 63;
  const int wm = w >> 1, wn = w & 1;
  const int fr = lane & 15, g = lane >> 4;
  const int lr = lane >> 3, ls = lane & 7;
  const int sslot = ls ^ lr;  // pre-swizzled k-slot (row&7 == lr)

  f32x4 acc[4][4];
  f32x4 z4 = {0.f, 0.f, 0.f, 0.f};
#pragma unroll
  for (int i = 0; i < 4; ++i)
#pragma unroll
    for (int j = 0; j < 4; ++j) acc[i][j] = z4;

  for (int ks = 0; ks < 10; ++ks) {
    const int k0 = ks * 64;
#pragma unroll
    for (int p = 0; p < 4; ++p) {
      int q = w * 4 + p;           // chunk: rows q*8 .. q*8+7
      int row = q * 8 + lr;
      gload_lds16(A + (size_t)(r0 + row) * NC + k0 + sslot * 8, sA + q * 512);
      gload_lds16(Bw + (size_t)(c0 + row) * NC + k0 + sslot * 8, sB + q * 512);
    }
    asm volatile("s_waitcnt vmcnt(0)" ::: "memory");
    __syncthreads();
#pragma unroll
    for (int kk = 0; kk < 2; ++kk) {
      bf16x8 af[4], bfr[4];
#pragma unroll
      for (int mt = 0; mt < 4; ++mt) {
        int row = wm * 64 + mt * 16 + fr;
        af[mt] = *(const bf16x8*)((const char*)sA + row * 128 +
                                  ((kk * 64 + g * 16) ^ ((row & 7) << 4)));
      }
#pragma unroll
      for (int nt = 0; nt < 4; ++nt) {
        int row = wn * 64 + nt * 16 + fr;
        bfr[nt] = *(const bf16x8*)((const char*)sB + row * 128 +
                                   ((kk * 64 + g * 16) ^ ((row & 7) << 4)));
      }
#pragma unroll
      for (int mt = 0; mt < 4; ++mt)
#pragma unroll
        for (int nt = 0; nt < 4; ++nt)
          acc[mt][nt] = mfma16(af[mt], bfr[nt], acc[mt][nt]);  // D: row<->n, col<->c
    }
    __syncthreads();
  }
  const int b = r0 >> 12, n0 = r0 & 4095;
  // D[row=g*4+r <-> n][col=fr <-> c]; write (B,C,N) f32 + bias
#pragma unroll
  for (int mt = 0; mt < 4; ++mt) {
    int n = n0 + wm * 64 + mt * 16 + g * 4;
#pragma unroll
    for (int nt = 0; nt < 4; ++nt) {
      int c = c0 + wn * 64 + nt * 16 + fr;
      float bv = bias[c];
      f32x4 o;
#pragma unroll
      for (int r2 = 0; r2 < 4; ++r2) o[r2] = acc[mt][nt][r2] + bv;
      *(f32x4*)(outf + (((size_t)(b * NC + c)) << 12) + n) = o;
    }
  }
}

// ---------------- A1: fused attention, one (b,h,64 q-rows) per block (R5 verbatim)
__global__ __launch_bounds__(256) void k_attn(const u16* __restrict__ qbf,
                                              const u16* __restrict__ kbf,
                                              const u16* __restrict__ vtbf,
                                              u16* __restrict__ obf) {
  __shared__ __align__(16) u16 sP[4][16][104];
  const int bid = blockIdx.x;
  const int n0 = (bid & 63) * 64, h = (bid >> 6) & 7, b = bid >> 9;
  const int t = threadIdx.x, w = t >> 6, lane = t & 63;
  const int fr = lane & 15, g = lane >> 4;

  const size_t qrow = ((size_t)(b * NN + n0 + w * 16 + fr)) * NC + h * NDH;
  bf16x8 qf[3];
#pragma unroll
  for (int kk = 0; kk < 3; ++kk) {
    int d0 = kk * 32 + g * 8;
    bf16x8 v = {};
    if (d0 < NDH) v = *(const bf16x8*)(qbf + qrow + d0);
    qf[kk] = v;
  }
  const size_t kbase = ((size_t)(b * NH + h)) * (80 * 80);
  f32x4 s[5];
  f32x4 z4 = {0.f, 0.f, 0.f, 0.f};
#pragma unroll
  for (int nt = 0; nt < 5; ++nt) s[nt] = z4;
#pragma unroll
  for (int nt = 0; nt < 5; ++nt) {
    const u16* krow = kbf + kbase + (size_t)(nt * 16 + fr) * 80;
#pragma unroll
    for (int kk = 0; kk < 3; ++kk) {
      int d0 = kk * 32 + g * 8;
      bf16x8 kv = {};
      if (d0 < NDH) kv = *(const bf16x8*)(krow + d0);
      s[nt] = mfma16(kv, qf[kk], s[nt]);
    }
  }
  const size_t vbase = ((size_t)(b * NH + h)) * (80 * 96);
  bf16x8 vf[5][3];
#pragma unroll
  for (int nt = 0; nt < 5; ++nt)
#pragma unroll
    for (int kk = 0; kk < 3; ++kk)
      vf[nt][kk] = *(const bf16x8*)(vtbf + vbase + (size_t)(nt * 16 + fr) * 96 +
                                    kk * 32 + g * 8);
  float sum = 0.f;
#pragma unroll
  for (int nt = 0; nt < 5; ++nt)
#pragma unroll
    for (int r = 0; r < 4; ++r) {
      int l = nt * 16 + g * 4 + r;
      float ev = (l < NL) ? __expf(s[nt][r]) : 0.f;
      s[nt][r] = ev;
      sum += ev;
    }
  sum += __shfl_xor(sum, 16);
  sum += __shfl_xor(sum, 32);
  float inv = 1.0f / sum;
#pragma unroll
  for (int nt = 0; nt < 5; ++nt) {
    u16x4 o;
#pragma unroll
    for (int r = 0; r < 4; ++r) o[r] = f2bf(s[nt][r] * inv);
    *(u16x4*)&sP[w][fr][nt * 16 + g * 4] = o;
  }
  __syncthreads();
  bf16x8 ap[3];
#pragma unroll
  for (int kk = 0; kk < 3; ++kk) {
    int l0 = kk * 32 + g * 8;
    bf16x8 v = {};
    if (l0 < 80) v = *(const bf16x8*)&sP[w][fr][l0];
    ap[kk] = v;
  }
  f32x4 o[5];
#pragma unroll
  for (int nt = 0; nt < 5; ++nt) o[nt] = z4;
#pragma unroll
  for (int nt = 0; nt < 5; ++nt)
#pragma unroll
    for (int kk = 0; kk < 3; ++kk)
      o[nt] = mfma16(ap[kk], vf[nt][kk], o[nt]);
#pragma unroll
  for (int nt = 0; nt < 5; ++nt)
#pragma unroll
    for (int r = 0; r < 4; ++r)
      obf[((size_t)(b * NN + n0 + w * 16 + g * 4 + r)) * NC + h * NDH + nt * 16 + fr] =
          f2bf(o[nt][r]);
}

extern "C" void kernel_launch(void* const* d_in, const int* in_sizes, int n_in,
                              void* d_out, int out_size, void* d_ws, size_t ws_size,
                              hipStream_t stream) {
  const float* hs  = (const float*)d_in[0];
  const float* ehs = (const float*)d_in[1];
  const float* Wq  = (const float*)d_in[2];
  const float* Wk  = (const float*)d_in[3];
  const float* Wv  = (const float*)d_in[4];
  const float* Wo  = (const float*)d_in[5];
  const float* bo  = (const float*)d_in[6];
  float* out = (float*)d_out;
  float* sal = out + (size_t)NB * NC * NN;

  u16* ws16 = (u16*)d_ws;
  const size_t xn = (size_t)NB * NN * NC;  // 20,971,520
  u16* xbf = ws16;            // also obf (xbf dead after k_kvg0)
  u16* qbf = ws16 + xn;
  u16* wqt = qbf + xn;
  u16* wot = wqt + (size_t)NC * NC;
  u16* kbf = wot + (size_t)NC * NC;                 // B*H*80*80
  u16* vtbf = kbf + (size_t)NB * NH * 80 * 80;      // B*H*80*96
  u16* obf = xbf;

  k_prep<<<6048, 256, 0, stream>>>(hs, Wq, Wo, xbf, wqt, wot, sal);
  k_kvg0<<<2240, 256, 0, stream>>>(ehs, Wk, Wv, kbf, vtbf, xbf, wqt, qbf);
  k_attn<<<NB * NH * 64, 256, 0, stream>>>(qbf, kbf, vtbf, obf);
  k_gemm_o<<<1280, 256, 0, stream>>>(obf, wot, bo, out);
}